// Round 1
// baseline (20.584 us; speedup 1.0000x reference)
//
#include <hip/hip_runtime.h>

// EUC classifier: scores[b,o] = -sum_c (w[o,c] - x[b,c])^2 / 64
// B=256, OUT=1000, C=512, fp32 in/out.

constexpr int B   = 256;
constexpr int OUT = 1000;
constexpr int C   = 512;

constexpr int BM = 32;   // batch rows per block
constexpr int BN = 32;   // out cols per block
constexpr int BK = 64;   // K chunk
constexpr float NEG_INV_TEMP = -1.0f / 64.0f;

__global__ __launch_bounds__(256, 2)
void euc_kernel(const float* __restrict__ x,
                const float* __restrict__ w,
                float* __restrict__ out) {
    // Transposed tiles, +2 pad keeps 8B alignment for paired reads and
    // breaks power-of-2 bank strides on the transposed writes.
    __shared__ float xs[BK][BM + 2];
    __shared__ float ws[BK][BN + 2];

    const int t  = threadIdx.x;
    const int rb = blockIdx.y * BM;   // batch-row base
    const int cb = blockIdx.x * BN;   // out-col base

    // compute-thread layout: 16x16, each thread owns 2x2 outputs
    const int tr = t >> 4;            // 0..15 -> rows 2tr, 2tr+1
    const int tc = t & 15;            // 0..15 -> cols 2tc, 2tc+1

    // staging layout: thread covers (sr, k=sk..sk+3) and (sr+16, same k)
    const int sr = t >> 4;            // 0..15
    const int sk = (t & 15) << 2;     // 0,4,...,60

    float acc00 = 0.f, acc01 = 0.f, acc10 = 0.f, acc11 = 0.f;

    for (int kc = 0; kc < C; kc += BK) {
        __syncthreads();  // protect previous iteration's reads

        // ---- stage x tile (always in-bounds: B=256 divisible by BM) ----
        {
            const float4 v0 = *reinterpret_cast<const float4*>(&x[(rb + sr)      * C + kc + sk]);
            const float4 v1 = *reinterpret_cast<const float4*>(&x[(rb + sr + 16) * C + kc + sk]);
            xs[sk + 0][sr] = v0.x;  xs[sk + 1][sr] = v0.y;
            xs[sk + 2][sr] = v0.z;  xs[sk + 3][sr] = v0.w;
            xs[sk + 0][sr + 16] = v1.x;  xs[sk + 1][sr + 16] = v1.y;
            xs[sk + 2][sr + 16] = v1.z;  xs[sk + 3][sr + 16] = v1.w;
        }
        // ---- stage w tile (guard o >= OUT with zeros; never written out) ----
        {
            const int o0 = cb + sr;
            const int o1 = cb + sr + 16;
            float4 v0 = make_float4(0.f, 0.f, 0.f, 0.f);
            float4 v1 = make_float4(0.f, 0.f, 0.f, 0.f);
            if (o0 < OUT) v0 = *reinterpret_cast<const float4*>(&w[o0 * C + kc + sk]);
            if (o1 < OUT) v1 = *reinterpret_cast<const float4*>(&w[o1 * C + kc + sk]);
            ws[sk + 0][sr] = v0.x;  ws[sk + 1][sr] = v0.y;
            ws[sk + 2][sr] = v0.z;  ws[sk + 3][sr] = v0.w;
            ws[sk + 0][sr + 16] = v1.x;  ws[sk + 1][sr + 16] = v1.y;
            ws[sk + 2][sr + 16] = v1.z;  ws[sk + 3][sr + 16] = v1.w;
        }
        __syncthreads();

        // ---- compute: 2x2 micro-tile over this K chunk ----
        #pragma unroll
        for (int k = 0; k < BK; ++k) {
            const float a0 = xs[k][2 * tr];
            const float a1 = xs[k][2 * tr + 1];
            const float b0 = ws[k][2 * tc];
            const float b1 = ws[k][2 * tc + 1];
            float d;
            d = a0 - b0; acc00 += d * d;
            d = a0 - b1; acc01 += d * d;
            d = a1 - b0; acc10 += d * d;
            d = a1 - b1; acc11 += d * d;
        }
    }

    // ---- epilogue: scores = -acc/64, guard cols >= OUT ----
    const int r0 = rb + 2 * tr;
    const int c0 = cb + 2 * tc;
    if (c0 + 1 < OUT) {
        out[(r0    ) * OUT + c0    ] = acc00 * NEG_INV_TEMP;
        out[(r0    ) * OUT + c0 + 1] = acc01 * NEG_INV_TEMP;
        out[(r0 + 1) * OUT + c0    ] = acc10 * NEG_INV_TEMP;
        out[(r0 + 1) * OUT + c0 + 1] = acc11 * NEG_INV_TEMP;
    } else if (c0 < OUT) {
        out[(r0    ) * OUT + c0] = acc00 * NEG_INV_TEMP;
        out[(r0 + 1) * OUT + c0] = acc10 * NEG_INV_TEMP;
    }
}

extern "C" void kernel_launch(void* const* d_in, const int* in_sizes, int n_in,
                              void* d_out, int out_size, void* d_ws, size_t ws_size,
                              hipStream_t stream) {
    const float* x = (const float*)d_in[0];   // (256, 1, 512)
    const float* w = (const float*)d_in[1];   // (1000, 512)
    float* out = (float*)d_out;               // (256, 1000)

    dim3 grid((OUT + BN - 1) / BN, B / BM);   // (32, 8) = 256 blocks
    dim3 block(256);
    euc_kernel<<<grid, block, 0, stream>>>(x, w, out);
}

// Round 2
// 9.823 us; speedup vs baseline: 2.0955x; 2.0955x over previous
//
#include <hip/hip_runtime.h>

// scores[b,o] = -||w_o - x_b||^2 / 64   via   (2*x.w - ||x||^2 - ||w||^2)/64
// B=256, OUT=1000, C=512, fp32 in/out. Cross term on bf16 MFMA, norms in fp32.

constexpr int OUTN = 1000;
constexpr int C_   = 512;

typedef __attribute__((ext_vector_type(8))) short bf16x8;
typedef __attribute__((ext_vector_type(4))) float f32x4;

// round-to-nearest-even f32 -> bf16 (finite inputs only)
__device__ __forceinline__ unsigned short f2bf(float f) {
    unsigned u = __float_as_uint(f);
    return (unsigned short)((u + 0x7fffu + ((u >> 16) & 1u)) >> 16);
}

__global__ __launch_bounds__(512, 2)
void euc_mfma(const float* __restrict__ x, const float* __restrict__ w,
              float* __restrict__ out) {
    // 32 rows x 512 k, bf16, granule(16B)-swizzled: granule g of row r stored
    // at granule index g ^ (r&7). 2 x 32 KiB = 64 KiB static LDS exactly.
    __shared__ unsigned short xs[32][512];
    __shared__ unsigned short ws[32][512];

    const int t    = threadIdx.x;
    const int lane = t & 63;
    const int wv   = t >> 6;              // wave 0..7
    const int rb   = blockIdx.y * 32;     // batch-row base
    const int cb   = blockIdx.x * 32;     // out-col base

    float nrm[8];                         // fp32 norms of the 8 rows this wave stages

    // ---- stage whole tiles (x: i=0..3, w: i=4..7); wave wv stages row 8*(i&3)+wv ----
    #pragma unroll
    for (int i = 0; i < 8; ++i) {
        const int  row = 8 * (i & 3) + wv;
        const bool isx = (i < 4);
        float4 v0 = make_float4(0.f, 0.f, 0.f, 0.f), v1 = v0;
        if (isx) {
            const float* s = &x[(rb + row) * C_ + lane * 8];
            v0 = *(const float4*)s;  v1 = *(const float4*)(s + 4);
        } else if (cb + row < OUTN) {
            const float* s = &w[(cb + row) * C_ + lane * 8];
            v0 = *(const float4*)s;  v1 = *(const float4*)(s + 4);
        }
        // fp32 partial norm of this row, butterfly-reduced across the wave
        float p = v0.x*v0.x + v0.y*v0.y + v0.z*v0.z + v0.w*v0.w
                + v1.x*v1.x + v1.y*v1.y + v1.z*v1.z + v1.w*v1.w;
        #pragma unroll
        for (int m = 1; m < 64; m <<= 1) p += __shfl_xor(p, m, 64);
        nrm[i] = p;
        // pack 8 bf16 and store one swizzled 16B granule (granule id = lane)
        union { unsigned short s[8]; int4 q; } u;
        u.s[0] = f2bf(v0.x); u.s[1] = f2bf(v0.y); u.s[2] = f2bf(v0.z); u.s[3] = f2bf(v0.w);
        u.s[4] = f2bf(v1.x); u.s[5] = f2bf(v1.y); u.s[6] = f2bf(v1.z); u.s[7] = f2bf(v1.w);
        const int g = lane ^ (row & 7);
        if (isx) *(int4*)&xs[row][g * 8] = u.q;
        else     *(int4*)&ws[row][g * 8] = u.q;
    }
    __syncthreads();

    // ---- MFMA: wave = quadrant q (16x16) x K-half h (256) ----
    const int q  = wv & 3, h = wv >> 2;
    const int qr = q >> 1, qc = q & 1;
    const int ra = 16 * qr + (lane & 15);   // x row for A frag
    const int rw = 16 * qc + (lane & 15);   // w row for B frag (B^T pattern)
    f32x4 acc = {0.f, 0.f, 0.f, 0.f};
    #pragma unroll
    for (int i = 0; i < 8; ++i) {
        const int gi = 32 * h + 4 * i + (lane >> 4);     // 16B-granule index along k
        const bf16x8 a = *(const bf16x8*)&xs[ra][(gi ^ (ra & 7)) * 8];
        const bf16x8 b = *(const bf16x8*)&ws[rw][(gi ^ (rw & 7)) * 8];
        acc = __builtin_amdgcn_mfma_f32_16x16x32_bf16(a, b, acc, 0, 0, 0);
    }
    __syncthreads();   // all tile reads done; LDS reusable as scratch

    char* sbase = (char*)&xs[0][0];
    // split-K partner (h==1) parks its partial C frag in LDS
    if (h == 1) *(f32x4*)(sbase + q * 1024 + lane * 16) = acc;
    // every wave publishes its 8 fp32 norms (idx 0..31 = x rows, 32..63 = w rows)
    float* nb = (float*)(sbase + 4096);
    if (lane == 0) {
        #pragma unroll
        for (int i = 0; i < 8; ++i) {
            const int row = 8 * (i & 3) + wv;
            nb[(i < 4) ? row : 32 + row] = nrm[i];
        }
    }
    __syncthreads();

    // ---- epilogue on h==0 waves: combine halves, add norms, scale, store ----
    if (h == 0) {
        const f32x4 p = *(const f32x4*)(sbase + q * 1024 + lane * 16);
        const int c = cb + 16 * qc + (lane & 15);
        if (c < OUTN) {
            const float nw = nb[32 + 16 * qc + (lane & 15)];
            #pragma unroll
            for (int j = 0; j < 4; ++j) {
                const int r = 16 * qr + (lane >> 4) * 4 + j;   // C/D: row=(l>>4)*4+j
                const float nx = nb[r];
                out[(rb + r) * OUTN + c] =
                    (2.f * (acc[j] + p[j]) - nx - nw) * 0.015625f;
            }
        }
    }
}

extern "C" void kernel_launch(void* const* d_in, const int* in_sizes, int n_in,
                              void* d_out, int out_size, void* d_ws, size_t ws_size,
                              hipStream_t stream) {
    const float* x = (const float*)d_in[0];   // (256, 1, 512)
    const float* w = (const float*)d_in[1];   // (1000, 512)
    float* out = (float*)d_out;               // (256, 1000)

    dim3 grid((OUTN + 31) / 32, 256 / 32);    // (32, 8) = 256 blocks
    dim3 block(512);                          // 8 waves, 2 waves/SIMD
    euc_mfma<<<grid, block, 0, stream>>>(x, w, out);
}

// Round 3
// 9.816 us; speedup vs baseline: 2.0969x; 1.0007x over previous
//
#include <hip/hip_runtime.h>
#include <hip/hip_bf16.h>

// scores[b,o] = -||w_o - x_b||^2 / 64  computed as  (2*x.w - ||x||^2 - ||w||^2)/64
// with x,w rounded to bf16: result is exactly -||bf16(w)-bf16(x)||^2/64 in fp32
// accumulation (MFMA). Norms are computed on the matrix cores from the same
// bf16 fragments (diag of mfma(f,f)) -- no shuffle reductions anywhere.
// B=256, OUT=1000, C=512, fp32 in/out.

constexpr int OUTN = 1000;
constexpr int C_   = 512;

typedef __attribute__((ext_vector_type(8))) short bf16x8;
typedef __attribute__((ext_vector_type(4))) float f32x4;

__device__ __forceinline__ unsigned short f2bf(float f) {
    __hip_bfloat16 b = __float2bfloat16(f);   // RTNE; compiler pairs into v_cvt_pk_bf16_f32
    return *reinterpret_cast<unsigned short*>(&b);
}

__global__ __launch_bounds__(512, 2)
void euc_mfma(const float* __restrict__ x, const float* __restrict__ w,
              float* __restrict__ out) {
    // 32 rows x 512 k, bf16, 16B-granule swizzle: granule g of row r lives at
    // index g ^ (r&7). Exactly 64 KiB static LDS; scratch regions reuse xs.
    __shared__ unsigned short xs[32][512];
    __shared__ unsigned short ws[32][512];

    const int t    = threadIdx.x;
    const int lane = t & 63;
    const int wv   = t >> 6;              // wave 0..7
    const int rb   = blockIdx.y * 32;     // batch-row base
    const int cb   = blockIdx.x * 32;     // out-col base

    // ---- stage tiles: wave wv stages rows 8*(i&3)+wv (x for i<4, w for i>=4) ----
    #pragma unroll
    for (int i = 0; i < 8; ++i) {
        const int  row = 8 * (i & 3) + wv;
        const bool isx = (i < 4);
        float4 v0 = make_float4(0.f, 0.f, 0.f, 0.f), v1 = v0;
        if (isx) {
            const float* s = &x[(rb + row) * C_ + lane * 8];
            v0 = *(const float4*)s;  v1 = *(const float4*)(s + 4);
        } else if (cb + row < OUTN) {
            const float* s = &w[(cb + row) * C_ + lane * 8];
            v0 = *(const float4*)s;  v1 = *(const float4*)(s + 4);
        }
        union { unsigned short s[8]; int4 q; } u;
        u.s[0] = f2bf(v0.x); u.s[1] = f2bf(v0.y); u.s[2] = f2bf(v0.z); u.s[3] = f2bf(v0.w);
        u.s[4] = f2bf(v1.x); u.s[5] = f2bf(v1.y); u.s[6] = f2bf(v1.z); u.s[7] = f2bf(v1.w);
        const int g = lane ^ (row & 7);
        if (isx) *(int4*)&xs[row][g * 8] = u.q;
        else     *(int4*)&ws[row][g * 8] = u.q;
    }
    __syncthreads();   // B1: tiles visible

    // ---- wave = quadrant q (16x16 output) x K-half h (256) ----
    const int q  = wv & 3, h = wv >> 2;
    const int qr = q >> 1, qc = q & 1;
    const int ra = 16 * qr + (lane & 15);   // x row for A frag
    const int rw = 16 * qc + (lane & 15);   // w row for B frag (B^T pattern)

    bf16x8 af[8], bf[8];
    f32x4 acc = {0.f, 0.f, 0.f, 0.f};
    #pragma unroll
    for (int i = 0; i < 8; ++i) {
        const int gi = 32 * h + 4 * i + (lane >> 4);     // 16B-granule index along k
        af[i] = *(const bf16x8*)&xs[ra][(gi ^ (ra & 7)) * 8];
        bf[i] = *(const bf16x8*)&ws[rw][(gi ^ (rw & 7)) * 8];
        acc = __builtin_amdgcn_mfma_f32_16x16x32_bf16(af[i], bf[i], acc, 0, 0, 0);
    }

    // ---- norms via MFMA diag, reusing register fragments (no extra LDS reads).
    // Job map: q0 -> x rows 0-15, q3 -> x rows 16-31, q2 -> w rows 0-15, q1 -> w 16-31.
    const bool useA = (q == 0) || (q == 3);
    f32x4 nacc = {0.f, 0.f, 0.f, 0.f};
    if (useA) {
        #pragma unroll
        for (int i = 0; i < 8; ++i)
            nacc = __builtin_amdgcn_mfma_f32_16x16x32_bf16(af[i], af[i], nacc, 0, 0, 0);
    } else {
        #pragma unroll
        for (int i = 0; i < 8; ++i)
            nacc = __builtin_amdgcn_mfma_f32_16x16x32_bf16(bf[i], bf[i], nacc, 0, 0, 0);
    }

    __syncthreads();   // B2: all tile ds_reads complete; LDS reusable as scratch

    char* sbase = (char*)&xs[0][0];
    float* nb = (float*)(sbase + 4096);   // nb[h*64 + idx]: 0..31 = x rows, 32..63 = w rows
    // split-K partner parks its partial C frag
    if (h == 1) *(f32x4*)(sbase + q * 1024 + lane * 16) = acc;
    // diagonal lanes publish this half's norms
    {
        const int base = useA ? 16 * qr : 32 + 16 * qc;
        #pragma unroll
        for (int j = 0; j < 4; ++j) {
            const int r = (lane >> 4) * 4 + j;           // C row within 16x16
            if ((lane & 15) == r) nb[h * 64 + base + r] = nacc[j];
        }
    }
    __syncthreads();   // B3: partials + norms visible

    // ---- epilogue on h==0 waves: combine halves, add norms, scale, store ----
    if (h == 0) {
        const f32x4 p = *(const f32x4*)(sbase + q * 1024 + lane * 16);
        const int cl = 16 * qc + (lane & 15);            // tile col 0..31
        const int c  = cb + cl;
        if (c < OUTN) {
            const float nw = nb[32 + cl] + nb[64 + 32 + cl];
            #pragma unroll
            for (int j = 0; j < 4; ++j) {
                const int r = 16 * qr + (lane >> 4) * 4 + j;   // tile row 0..31
                const float nx = nb[r] + nb[64 + r];
                out[(rb + r) * OUTN + c] =
                    (2.f * (acc[j] + p[j]) - nx - nw) * 0.015625f;
            }
        }
    }
}

extern "C" void kernel_launch(void* const* d_in, const int* in_sizes, int n_in,
                              void* d_out, int out_size, void* d_ws, size_t ws_size,
                              hipStream_t stream) {
    const float* x = (const float*)d_in[0];   // (256, 1, 512)
    const float* w = (const float*)d_in[1];   // (1000, 512)
    float* out = (float*)d_out;               // (256, 1000)

    dim3 grid((OUTN + 31) / 32, 256 / 32);    // (32, 8) = 256 blocks, 1 per CU
    dim3 block(512);                          // 8 waves
    euc_mfma<<<grid, block, 0, stream>>>(x, w, out);
}

// Round 4
// 9.785 us; speedup vs baseline: 2.1036x; 1.0032x over previous
//
#include <hip/hip_runtime.h>
#include <hip/hip_bf16.h>

// scores[b,o] = -||w_o - x_b||^2 / 64  via  (2*x.w - ||x||^2 - ||w||^2)/64
// with x,w rounded to bf16; cross term AND norms on matrix cores (norms = diag
// of mfma(f,f) on the same register fragments). fp32 accumulation throughout.
// B=256, OUT=1000, C=512, fp32 in/out.
// r4 change: 16 waves/block (4 waves/SIMD) + 4-way split-K to hide cold-HBM
// staging latency (L3 is wiped by the harness's 256MB poison fills).

constexpr int OUTN = 1000;
constexpr int C_   = 512;

typedef __attribute__((ext_vector_type(8))) short bf16x8;
typedef __attribute__((ext_vector_type(4))) float f32x4;

__device__ __forceinline__ unsigned short f2bf(float f) {
    __hip_bfloat16 b = __float2bfloat16(f);   // RTNE
    return *reinterpret_cast<unsigned short*>(&b);
}

__global__ __launch_bounds__(1024, 4)
void euc_mfma(const float* __restrict__ x, const float* __restrict__ w,
              float* __restrict__ out) {
    // 32 rows x 512 k each, bf16, 16B-granule swizzle: granule g of row r at
    // index g ^ (r&7). 64 KiB static LDS; scratch reuses xs after B2.
    __shared__ unsigned short xs[32][512];
    __shared__ unsigned short ws[32][512];

    const int t    = threadIdx.x;
    const int lane = t & 63;
    const int wv   = t >> 6;              // wave 0..15
    const int rb   = blockIdx.y * 32;     // batch-row base
    const int cb   = blockIdx.x * 32;     // out-col base

    // ---- stage: 4096 granules (64 rows x 64), 4 per thread; each wave covers
    // whole rows (coalesced 2KB per row). rows 0..31 = x, 32..63 = w.
    #pragma unroll
    for (int j = 0; j < 4; ++j) {
        const int gidx = j * 1024 + t;    // 0..4095
        const int row  = gidx >> 6;       // 0..63
        const int g    = gidx & 63;       // 8-float granule within row
        float4 v0 = make_float4(0.f, 0.f, 0.f, 0.f), v1 = v0;
        if (row < 32) {
            const float* s = &x[(rb + row) * C_ + g * 8];
            v0 = *(const float4*)s;  v1 = *(const float4*)(s + 4);
        } else if (cb + row - 32 < OUTN) {
            const float* s = &w[(cb + row - 32) * C_ + g * 8];
            v0 = *(const float4*)s;  v1 = *(const float4*)(s + 4);
        }
        union { unsigned short s[8]; int4 q; } u;
        u.s[0] = f2bf(v0.x); u.s[1] = f2bf(v0.y); u.s[2] = f2bf(v0.z); u.s[3] = f2bf(v0.w);
        u.s[4] = f2bf(v1.x); u.s[5] = f2bf(v1.y); u.s[6] = f2bf(v1.z); u.s[7] = f2bf(v1.w);
        const int gs = (g ^ (row & 7)) * 8;
        if (row < 32) *(int4*)&xs[row][gs]      = u.q;
        else          *(int4*)&ws[row - 32][gs] = u.q;
    }
    __syncthreads();   // B1: tiles visible

    // ---- wave = quadrant q (16x16 output) x K-quarter h (128) ----
    const int q  = wv & 3, h = wv >> 2;     // h 0..3
    const int qr = q >> 1, qc = q & 1;
    const int ra = 16 * qr + (lane & 15);   // x row for A frag
    const int rw = 16 * qc + (lane & 15);   // w row for B frag (B^T pattern)

    bf16x8 af[4], bff[4];
    f32x4 acc = {0.f, 0.f, 0.f, 0.f};
    #pragma unroll
    for (int i = 0; i < 4; ++i) {
        const int gi = 16 * h + 4 * i + (lane >> 4);    // 16B-granule along k
        af[i]  = *(const bf16x8*)&xs[ra][(gi ^ (ra & 7)) * 8];
        bff[i] = *(const bf16x8*)&ws[rw][(gi ^ (rw & 7)) * 8];
        acc = __builtin_amdgcn_mfma_f32_16x16x32_bf16(af[i], bff[i], acc, 0, 0, 0);
    }

    // norms via MFMA diag on own fragments.
    // q0 -> x rows 0-15, q3 -> x rows 16-31, q2 -> w rows 0-15, q1 -> w 16-31.
    const bool useA = (q == 0) || (q == 3);
    f32x4 nacc = {0.f, 0.f, 0.f, 0.f};
    #pragma unroll
    for (int i = 0; i < 4; ++i) {
        const bf16x8 f = useA ? af[i] : bff[i];
        nacc = __builtin_amdgcn_mfma_f32_16x16x32_bf16(f, f, nacc, 0, 0, 0);
    }
    __syncthreads();   // B2: all tile ds_reads complete; LDS reusable

    char* sbase = (char*)&xs[0][0];
    // split-K partners (h=1..3) park partial C frags: 12 KiB
    if (h) *(f32x4*)(sbase + ((h - 1) * 4 + q) * 1024 + lane * 16) = acc;
    // diagonal lanes publish this quarter's norms: nb[h*64 + idx], idx 0..31=x, 32..63=w
    float* nb = (float*)(sbase + 12288);
    {
        const int base = useA ? 16 * qr : 32 + 16 * qc;
        #pragma unroll
        for (int j = 0; j < 4; ++j) {
            const int r = (lane >> 4) * 4 + j;          // C row within 16x16
            if ((lane & 15) == r) nb[h * 64 + base + r] = nacc[j];
        }
    }
    __syncthreads();   // B3: partials + norms visible

    // ---- epilogue on h==0 waves: sum 4 K-quarters, add norms, scale, store ----
    if (h == 0) {
        #pragma unroll
        for (int p = 0; p < 3; ++p) {
            const f32x4 v = *(const f32x4*)(sbase + (p * 4 + q) * 1024 + lane * 16);
            acc[0] += v[0]; acc[1] += v[1]; acc[2] += v[2]; acc[3] += v[3];
        }
        const int cl = 16 * qc + (lane & 15);           // tile col 0..31
        const int c  = cb + cl;
        if (c < OUTN) {
            const float nw = nb[32 + cl] + nb[64 + 32 + cl] + nb[128 + 32 + cl] + nb[192 + 32 + cl];
            #pragma unroll
            for (int j = 0; j < 4; ++j) {
                const int r = 16 * qr + (lane >> 4) * 4 + j;   // tile row 0..31
                const float nx = nb[r] + nb[64 + r] + nb[128 + r] + nb[192 + r];
                out[(rb + r) * OUTN + c] = (2.f * acc[j] - nx - nw) * 0.015625f;
            }
        }
    }
}

extern "C" void kernel_launch(void* const* d_in, const int* in_sizes, int n_in,
                              void* d_out, int out_size, void* d_ws, size_t ws_size,
                              hipStream_t stream) {
    const float* x = (const float*)d_in[0];   // (256, 1, 512)
    const float* w = (const float*)d_in[1];   // (1000, 512)
    float* out = (float*)d_out;               // (256, 1000)

    dim3 grid((OUTN + 31) / 32, 256 / 32);    // (32, 8) = 256 blocks, 1 per CU
    dim3 block(1024);                         // 16 waves, 4 waves/SIMD
    euc_mfma<<<grid, block, 0, stream>>>(x, w, out);
}